// Round 3
// baseline (1294.346 us; speedup 1.0000x reference)
//
#include <hip/hip_runtime.h>
#include <hip/hip_bf16.h>

#define T_TOK 8192
#define HDIM  1024
#define IDIM  4096
#define NEXP  8
#define MAXTILE 136   // sum ceil(cnt_e/128) <= 16384/128 + 8

typedef __bf16 bf16x8 __attribute__((ext_vector_type(8)));
typedef float  f32x4  __attribute__((ext_vector_type(4)));

typedef __attribute__((address_space(3))) unsigned int       lds_u32;
typedef const __attribute__((address_space(1))) unsigned int glb_u32;

__device__ __forceinline__ void gld16(void* lds, const void* g) {
    // async global->LDS: wave writes 1KiB at (uniform lds base) + lane*16
    __builtin_amdgcn_global_load_lds((glb_u32*)g, (lds_u32*)lds, 16, 0, 0);
}

// ---------------- hs fp32 -> bf16 ------------------------------------------
__global__ __launch_bounds__(256) void convert_hs_kernel(
    const float* __restrict__ hs, __bf16* __restrict__ hsb)
{
    size_t i = ((size_t)blockIdx.x * 256 + threadIdx.x) * 8;
    float4 a = *(const float4*)(hs + i);
    float4 b = *(const float4*)(hs + i + 4);
    bf16x8 v;
    v[0] = (__bf16)a.x; v[1] = (__bf16)a.y; v[2] = (__bf16)a.z; v[3] = (__bf16)a.w;
    v[4] = (__bf16)b.x; v[5] = (__bf16)b.y; v[6] = (__bf16)b.z; v[7] = (__bf16)b.w;
    *(bf16x8*)(hsb + i) = v;
}

// ---------------- weights fp32 [K][N] -> bf16 [N][K] (per expert) ----------
__global__ __launch_bounds__(256) void transpose_w_kernel(
    const float* __restrict__ gw, const float* __restrict__ uw,
    const float* __restrict__ dw,
    __bf16* __restrict__ Gt, __bf16* __restrict__ Ut, __bf16* __restrict__ Dt)
{
    const int z = blockIdx.y, mat = z >> 3, e = z & 7;
    const float* src; __bf16* dst; int R, C;
    if (mat == 0)      { src = gw; dst = Gt; R = HDIM; C = IDIM; }
    else if (mat == 1) { src = uw; dst = Ut; R = HDIM; C = IDIM; }
    else               { src = dw; dst = Dt; R = IDIM; C = HDIM; }
    src += (size_t)e * HDIM * IDIM;
    dst += (size_t)e * HDIM * IDIM;

    const int tilesC = C >> 6;
    const int tx = blockIdx.x % tilesC, ty = blockIdx.x / tilesC;
    const int r0 = ty * 64, c0 = tx * 64;

    __shared__ __bf16 Lt[64][72];

    const int tr  = threadIdx.x >> 4;
    const int tc4 = (threadIdx.x & 15) * 4;
#pragma unroll
    for (int p = 0; p < 4; ++p) {
        int r = p * 16 + tr;
        float4 v = *(const float4*)(src + (size_t)(r0 + r) * C + c0 + tc4);
        Lt[tc4 + 0][r] = (__bf16)v.x;
        Lt[tc4 + 1][r] = (__bf16)v.y;
        Lt[tc4 + 2][r] = (__bf16)v.z;
        Lt[tc4 + 3][r] = (__bf16)v.w;
    }
    __syncthreads();

    const int oc  = threadIdx.x >> 3;
    const int or8 = (threadIdx.x & 7) * 8;
#pragma unroll
    for (int p = 0; p < 2; ++p) {
        int c = oc + p * 32;
        bf16x8 v = *(const bf16x8*)(&Lt[c][or8]);
        *(bf16x8*)(dst + (size_t)(c0 + c) * R + r0 + or8) = v;
    }
}

// ---------------- router: fp64 logits, top-2 --------------------------------
__global__ __launch_bounds__(256) void router_kernel(
    const float* __restrict__ hs, const float* __restrict__ gpw,
    int* __restrict__ ca, int* __restrict__ cb,
    float* __restrict__ wa, float* __restrict__ wb)
{
    const int wv = threadIdx.x >> 6, lane = threadIdx.x & 63;
    const int t  = blockIdx.x * 4 + wv;
    const float* hrow = hs + (size_t)t * HDIM;

    double acc[NEXP];
#pragma unroll
    for (int e = 0; e < NEXP; ++e) acc[e] = 0.0;

#pragma unroll
    for (int it = 0; it < HDIM / 64; ++it) {
        int i = lane + it * 64;
        double x = (double)hrow[i];
#pragma unroll
        for (int e = 0; e < NEXP; ++e)
            acc[e] += x * (double)gpw[e * HDIM + i];
    }
#pragma unroll
    for (int e = 0; e < NEXP; ++e)
#pragma unroll
        for (int m = 32; m > 0; m >>= 1)
            acc[e] += __shfl_xor(acc[e], m);

    if (lane == 0) {
        int a = 0;
#pragma unroll
        for (int e = 1; e < NEXP; ++e) if (acc[e] > acc[a]) a = e;
        int b = (a == 0) ? 1 : 0;
#pragma unroll
        for (int e = 0; e < NEXP; ++e) if (e != a && acc[e] > acc[b]) b = e;
        double wA = 1.0 / (1.0 + exp(acc[b] - acc[a]));
        ca[t] = a; cb[t] = b;
        wa[t] = (float)wA; wb[t] = (float)(1.0 - wA);
    }
}

// ---------------- build per-expert lists (deterministic scan) ---------------
__global__ __launch_bounds__(256) void build_lists_kernel(
    const int* __restrict__ ca, const int* __restrict__ cb,
    const float* __restrict__ wa, const float* __restrict__ wb,
    int* __restrict__ lists, float* __restrict__ wlists, int* __restrict__ counts)
{
    const int e = blockIdx.x;
    const int tid = threadIdx.x, wv = tid >> 6, lane = tid & 63;
    __shared__ int wsum[4];
    int base = 0;
    for (int t0 = 0; t0 < T_TOK; t0 += 256) {
        int t  = t0 + tid;
        int m2 = (cb[t] == e);
        int m  = (ca[t] == e) | m2;
        unsigned long long bal = __ballot(m);
        int my = __popcll(bal & ((1ull << lane) - 1ull));
        if (lane == 0) wsum[wv] = __popcll(bal);
        __syncthreads();
        int off = 0;
        for (int w2 = 0; w2 < wv; ++w2) off += wsum[w2];
        int tot = wsum[0] + wsum[1] + wsum[2] + wsum[3];
        if (m) {
            int pos = base + off + my;
            lists[e * T_TOK + pos]  = t * 2 + m2;
            wlists[e * T_TOK + pos] = m2 ? wb[t] : wa[t];
        }
        base += tot;
        __syncthreads();
    }
    if (tid == 0) counts[e] = base;
}

// ---------------- tile plan: flatten (expert, row-tile) ---------------------
__global__ void plan_kernel(const int* __restrict__ counts,
                            int* __restrict__ tileE, int* __restrict__ tileB,
                            int* __restrict__ ntiles)
{
    if (threadIdx.x == 0 && blockIdx.x == 0) {
        int t = 0;
        for (int e = 0; e < NEXP; ++e) {
            int nt = (counts[e] + 127) >> 7;
            for (int i = 0; i < nt; ++i) { tileE[t] = e; tileB[t] = i * 128; ++t; }
        }
        ntiles[0] = t;
    }
}

// ---------------- FFN1: h = silu(x@G)*(x@U), 128x128 tile, BK=64, swizzled --
__global__ __launch_bounds__(256) void ffn1_kernel(
    const __bf16* __restrict__ hsb, const __bf16* __restrict__ Gt,
    const __bf16* __restrict__ Ut, const int* __restrict__ counts,
    const int* __restrict__ lists,
    const int* __restrict__ tileE, const int* __restrict__ tileB,
    const int* __restrict__ ntiles, __bf16* __restrict__ hbuf)
{
    const int tile = blockIdx.y;
    if (tile >= ntiles[0]) return;
    const int e   = tileE[tile];
    const int m0  = tileB[tile];
    const int cnt = counts[e];
    const int n0  = blockIdx.x * 128;
    const int tid = threadIdx.x;
    const int wv  = tid >> 6, lane = tid & 63;

    __shared__ int    toks[128];
    __shared__ __bf16 As[128][64];
    __shared__ __bf16 Bg[128][64];
    __shared__ __bf16 Bu[128][64];

    if (tid < 128) {
        int idx = m0 + tid;
        toks[tid] = lists[e * T_TOK + (idx < cnt ? idx : m0)];
    }
    __syncthreads();

    // --- staging addressing: chunk j = rows [wv*32+j*8, +8), lane -> (lr,p)
    const int lr = lane >> 3, p = lane & 7;
    const __bf16* Ge = Gt + (size_t)e * IDIM * HDIM;
    const __bf16* Ue = Ut + (size_t)e * IDIM * HDIM;
    unsigned offA[4], offB[4];
#pragma unroll
    for (int j = 0; j < 4; ++j) {
        int r  = wv * 32 + j * 8 + lr;
        int sg = (p - r) & 7;                 // logical 16B segment this lane fetches
        offA[j] = (unsigned)((toks[r] >> 1) * (HDIM * 2) + sg * 16);
        offB[j] = (unsigned)((n0 + r) * (HDIM * 2) + sg * 16);
    }

    const int wm = (wv >> 1) * 64, wn = (wv & 1) * 64;
    const int fr = lane & 15, fq = lane >> 4;
    const char* Ab = (const char*)&As[0][0];
    const char* Gb = (const char*)&Bg[0][0];
    const char* Ub = (const char*)&Bu[0][0];

    f32x4 accg[4][4], accu[4][4];
#pragma unroll
    for (int i = 0; i < 4; ++i)
#pragma unroll
        for (int j = 0; j < 4; ++j) { accg[i][j] = (f32x4)0.0f; accu[i][j] = (f32x4)0.0f; }

    for (int it = 0; it < HDIM / 64; ++it) {
#pragma unroll
        for (int j = 0; j < 4; ++j) {
            int R0 = wv * 32 + j * 8;
            gld16(&As[R0][0], (const char*)hsb + offA[j]);
            gld16(&Bg[R0][0], (const char*)Ge  + offB[j]);
            gld16(&Bu[R0][0], (const char*)Ue  + offB[j]);
            offA[j] += 128; offB[j] += 128;
        }
        __syncthreads();

#pragma unroll
        for (int k2 = 0; k2 < 2; ++k2) {
            bf16x8 a[4], bg[4], bu[4];
#pragma unroll
            for (int mi = 0; mi < 4; ++mi) {
                int r = wm + mi * 16 + fr;
                a[mi] = *(const bf16x8*)(Ab + r * 128 + (((fq + k2 * 4 + r) & 7) << 4));
            }
#pragma unroll
            for (int ni = 0; ni < 4; ++ni) {
                int r = wn + ni * 16 + fr;
                int o = r * 128 + (((fq + k2 * 4 + r) & 7) << 4);
                bg[ni] = *(const bf16x8*)(Gb + o);
                bu[ni] = *(const bf16x8*)(Ub + o);
            }
#pragma unroll
            for (int mi = 0; mi < 4; ++mi)
#pragma unroll
                for (int ni = 0; ni < 4; ++ni) {
                    accg[mi][ni] = __builtin_amdgcn_mfma_f32_16x16x32_bf16(a[mi], bg[ni], accg[mi][ni], 0, 0, 0);
                    accu[mi][ni] = __builtin_amdgcn_mfma_f32_16x16x32_bf16(a[mi], bu[ni], accu[mi][ni], 0, 0, 0);
                }
        }
        __syncthreads();
    }

#pragma unroll
    for (int mi = 0; mi < 4; ++mi)
#pragma unroll
        for (int r4 = 0; r4 < 4; ++r4) {
            int row = wm + mi * 16 + fq * 4 + r4;
            if (m0 + row < cnt) {
                __bf16* dst = hbuf + (size_t)toks[row] * IDIM + n0 + wn + fr;
#pragma unroll
                for (int ni = 0; ni < 4; ++ni) {
                    float g = accg[mi][ni][r4], u = accu[mi][ni][r4];
                    dst[ni * 16] = (__bf16)(g * (1.0f / (1.0f + __expf(-g))) * u);
                }
            }
        }
}

// ---------------- FFN2: out[tok] += w * (h @ Dt), 128x128, BK=64, swizzled --
__global__ __launch_bounds__(256) void ffn2_kernel(
    const __bf16* __restrict__ hbuf, const __bf16* __restrict__ Dt,
    const int* __restrict__ counts, const int* __restrict__ lists,
    const float* __restrict__ wlists,
    const int* __restrict__ tileE, const int* __restrict__ tileB,
    const int* __restrict__ ntiles, float* __restrict__ out)
{
    const int tile = blockIdx.y;
    if (tile >= ntiles[0]) return;
    const int e   = tileE[tile];
    const int m0  = tileB[tile];
    const int cnt = counts[e];
    const int n0  = blockIdx.x * 128;
    const int tid = threadIdx.x;
    const int wv  = tid >> 6, lane = tid & 63;

    __shared__ int    toks[128];
    __shared__ float  wts[128];
    __shared__ __bf16 As[128][64];
    __shared__ __bf16 Bd[128][64];

    if (tid < 128) {
        int idx  = m0 + tid;
        int cidx = idx < cnt ? idx : m0;
        toks[tid] = lists[e * T_TOK + cidx];
        wts[tid]  = wlists[e * T_TOK + cidx];
    }
    __syncthreads();

    const int lr = lane >> 3, p = lane & 7;
    const __bf16* De = Dt + (size_t)e * HDIM * IDIM;
    unsigned offA[4], offB[4];
#pragma unroll
    for (int j = 0; j < 4; ++j) {
        int r  = wv * 32 + j * 8 + lr;
        int sg = (p - r) & 7;
        offA[j] = (unsigned)(toks[r] * (IDIM * 2) + sg * 16);
        offB[j] = (unsigned)((n0 + r) * (IDIM * 2) + sg * 16);
    }

    const int wm = (wv >> 1) * 64, wn = (wv & 1) * 64;
    const int fr = lane & 15, fq = lane >> 4;
    const char* Ab = (const char*)&As[0][0];
    const char* Db = (const char*)&Bd[0][0];

    f32x4 acc[4][4];
#pragma unroll
    for (int i = 0; i < 4; ++i)
#pragma unroll
        for (int j = 0; j < 4; ++j) acc[i][j] = (f32x4)0.0f;

    for (int it = 0; it < IDIM / 64; ++it) {
#pragma unroll
        for (int j = 0; j < 4; ++j) {
            int R0 = wv * 32 + j * 8;
            gld16(&As[R0][0], (const char*)hbuf + offA[j]);
            gld16(&Bd[R0][0], (const char*)De   + offB[j]);
            offA[j] += 128; offB[j] += 128;
        }
        __syncthreads();

#pragma unroll
        for (int k2 = 0; k2 < 2; ++k2) {
            bf16x8 a[4], b[4];
#pragma unroll
            for (int mi = 0; mi < 4; ++mi) {
                int r = wm + mi * 16 + fr;
                a[mi] = *(const bf16x8*)(Ab + r * 128 + (((fq + k2 * 4 + r) & 7) << 4));
            }
#pragma unroll
            for (int ni = 0; ni < 4; ++ni) {
                int r = wn + ni * 16 + fr;
                b[ni] = *(const bf16x8*)(Db + r * 128 + (((fq + k2 * 4 + r) & 7) << 4));
            }
#pragma unroll
            for (int mi = 0; mi < 4; ++mi)
#pragma unroll
                for (int ni = 0; ni < 4; ++ni)
                    acc[mi][ni] = __builtin_amdgcn_mfma_f32_16x16x32_bf16(a[mi], b[ni], acc[mi][ni], 0, 0, 0);
        }
        __syncthreads();
    }

#pragma unroll
    for (int mi = 0; mi < 4; ++mi)
#pragma unroll
        for (int r4 = 0; r4 < 4; ++r4) {
            int row = wm + mi * 16 + fq * 4 + r4;
            if (m0 + row < cnt) {
                int   tok = toks[row] >> 1;
                float w   = wts[row];
                float* dst = out + (size_t)tok * HDIM + n0 + wn + fr;
#pragma unroll
                for (int ni = 0; ni < 4; ++ni)
                    atomicAdd(&dst[ni * 16], w * acc[mi][ni][r4]);
            }
        }
}

// ---------------------------------------------------------------------------
extern "C" void kernel_launch(void* const* d_in, const int* in_sizes, int n_in,
                              void* d_out, int out_size, void* d_ws, size_t ws_size,
                              hipStream_t stream)
{
    const float* hs  = (const float*)d_in[0];
    const float* gpw = (const float*)d_in[1];
    const float* gw  = (const float*)d_in[2];
    const float* uw  = (const float*)d_in[3];
    const float* dw  = (const float*)d_in[4];
    float* out = (float*)d_out;

    char* p = (char*)d_ws;
    __bf16* hsb  = (__bf16*)p;  p += (size_t)T_TOK * HDIM * 2;
    __bf16* Gt   = (__bf16*)p;  p += (size_t)NEXP * IDIM * HDIM * 2;
    __bf16* Ut   = (__bf16*)p;  p += (size_t)NEXP * IDIM * HDIM * 2;
    __bf16* Dt   = (__bf16*)p;  p += (size_t)NEXP * HDIM * IDIM * 2;
    __bf16* hbuf = (__bf16*)p;  p += (size_t)2 * T_TOK * IDIM * 2;
    int*    lists  = (int*)p;   p += (size_t)NEXP * T_TOK * 4;
    float*  wlists = (float*)p; p += (size_t)NEXP * T_TOK * 4;
    int*    ca = (int*)p;       p += (size_t)T_TOK * 4;
    int*    cb = (int*)p;       p += (size_t)T_TOK * 4;
    float*  wa = (float*)p;     p += (size_t)T_TOK * 4;
    float*  wb = (float*)p;     p += (size_t)T_TOK * 4;
    int*    counts = (int*)p;   p += 256;
    int*    tileE  = (int*)p;   p += MAXTILE * 4;
    int*    tileB  = (int*)p;   p += MAXTILE * 4;
    int*    ntiles = (int*)p;

    hipMemsetAsync(out, 0, (size_t)T_TOK * HDIM * sizeof(float), stream);

    convert_hs_kernel<<<T_TOK * HDIM / 2048, 256, 0, stream>>>(hs, hsb);
    transpose_w_kernel<<<dim3(1024, 24), 256, 0, stream>>>(gw, uw, dw, Gt, Ut, Dt);
    router_kernel<<<T_TOK / 4, 256, 0, stream>>>(hs, gpw, ca, cb, wa, wb);
    build_lists_kernel<<<NEXP, 256, 0, stream>>>(ca, cb, wa, wb, lists, wlists, counts);
    plan_kernel<<<1, 64, 0, stream>>>(counts, tileE, tileB, ntiles);

    ffn1_kernel<<<dim3(IDIM / 128, MAXTILE), 256, 0, stream>>>(
        hsb, Gt, Ut, counts, lists, tileE, tileB, ntiles, hbuf);
    ffn2_kernel<<<dim3(HDIM / 128, MAXTILE), 256, 0, stream>>>(
        hbuf, Dt, counts, lists, wlists, tileE, tileB, ntiles, out);
}